// Round 8
// baseline (206.221 us; speedup 1.0000x reference)
//
#include <hip/hip_runtime.h>
#include <math.h>

typedef unsigned int   u32;
typedef unsigned long long u64;

#define BATCH   8
#define NDATA   8192
#define NPOINT  1024
#define NSAMPLE 32
#define CFEAT   64
#define ROWF    67          // 3 xyz + 64 feat
#define MAXCAND 128         // P(#in-radius > 128) ~ 1e-60 for this data (lambda<=~18)

// f32-element offsets of the concatenated outputs
#define OUT_IDX (BATCH*NPOINT*NSAMPLE*ROWF)              // 17563648
#define OUT_GX  (OUT_IDX + BATCH*NPOINT*NSAMPLE)         // 17825792

// f32 -> bf16 (RNE) -> f32: match the harness's bf16-rounded np reference
__device__ __forceinline__ float rnbf(float f) {
    u32 b = __float_as_uint(f);
    b += 0x7FFFu + ((b >> 16) & 1u);
    return __uint_as_float(b & 0xFFFF0000u);
}
__device__ __forceinline__ int clampidx(int v) {
    return (v < 0) ? 0 : (v > NDATA-1 ? NDATA-1 : v);
}

// one wave per query; 4 queries per block (all same batch since 1024 % 4 == 0)
__global__ __launch_bounds__(256)
void grouping_kernel(const float* __restrict__ new_xyz,
                     const float* __restrict__ xyz,
                     const float* __restrict__ points,
                     float* __restrict__ out, float T)
{
    __shared__ float cand_s[4][MAXCAND];   // f32 sqrt of d2, slot order = ascending idx
    __shared__ int   cand_i[4][MAXCAND];
    __shared__ int   sel[4][NSAMPLE];

    const int tid  = threadIdx.x;
    const int wv   = tid >> 6;
    const int lane = tid & 63;
    const int q    = blockIdx.x * 4 + wv;    // global query id, < 8192
    const int b    = q >> 10;                // batch (NPOINT = 1024)

    if (lane < NSAMPLE) sel[wv][lane] = 0;   // same-wave init; ordered before later writes

    const float qx = new_xyz[q*3 + 0];
    const float qy = new_xyz[q*3 + 1];
    const float qz = new_xyz[q*3 + 2];
    const float* bx = xyz + (size_t)b * NDATA * 3;   // 96 KB/batch, L2-resident

    // ---- scan: argmin + ballot-compacted in-radius candidates ----
    float mind = 3.402823466e38f; int mini = 0;      // per-lane (d2, lowest idx)
    int n = 0;                                        // wave-uniform candidate count
    const u64 ltmask = (1ull << lane) - 1ull;
    const float* ptr = bx + (size_t)lane * 3;

    #pragma unroll 2
    for (int k = 0; k < NDATA/64; ++k) {
        int i = (k << 6) + lane;
        float x = ptr[0], y = ptr[1], z = ptr[2];
        ptr += 192;                                   // 64 points * 3
        // exact np f32 semantics: no FMA, left-to-right sum
        float dx = __fsub_rn(x, qx), dy = __fsub_rn(y, qy), dz = __fsub_rn(z, qz);
        float d2 = __fadd_rn(__fadd_rn(__fmul_rn(dx,dx), __fmul_rn(dy,dy)),
                             __fmul_rn(dz,dz));
        if (d2 < mind) { mind = d2; mini = i; }       // strict <: lowest idx per lane
        bool c = d2 < T;                              // == sqrtf(d2) < 0.2f (monotone)
        u64 m = __ballot(c);
        if (c) {
            int pos = n + (int)__popcll(m & ltmask);
            if (pos < MAXCAND) {
                cand_s[wv][pos] = __fsqrt_rn(d2);     // ref sorts the f32 norm
                cand_i[wv][pos] = i;
            }
        }
        n += (int)__popcll(m);
    }
    if (n > MAXCAND) n = MAXCAND;

    // wave-reduce argmin for empty-ball padding: np tie rule is on sqrt values
    float minS = __fsqrt_rn(mind);
    for (int off = 32; off; off >>= 1) {
        float os = __shfl_xor(minS, off);
        int   oi = __shfl_xor(mini, off);
        if (os < minS || (os == minS && oi < mini)) { minS = os; mini = oi; }
    }

    __syncthreads();   // publish compaction writes (uniform: fixed 128 iters)

    // ---- parallel rank-place: (s, slot) lex == stable argsort by distance ----
    const int nsel = n < NSAMPLE ? n : NSAMPLE;
    for (int k = lane; k < n; k += 64) {
        float sk = cand_s[wv][k];
        int r = 0;
        for (int mm = 0; mm < n; ++mm) {              // broadcast LDS reads, conflict-free
            float sm = cand_s[wv][mm];
            r += (int)((sm < sk) | ((sm == sk) & (mm < k)));
        }
        if (r < NSAMPLE) sel[wv][r] = clampidx(cand_i[wv][k]);
    }
    __syncthreads();
    if (lane >= nsel && lane < NSAMPLE) {
        int pad = (n > 0) ? sel[wv][0] : clampidx(mini);   // sorted_idx[0]
        sel[wv][lane] = pad;
    }
    __syncthreads();

    // ---- outputs: f32 stores, values pre-rounded through bf16 ----
    // idx  (chunk 1)
    if (lane < NSAMPLE)
        out[OUT_IDX + (size_t)q*NSAMPLE + lane] = rnbf((float)sel[wv][lane]);

    // grouped_xyz (chunk 2) + the xyz columns of new_points (chunk 0)
    for (int e = lane; e < NSAMPLE*3; e += 64) {
        int sR = e / 3, c = e - sR*3;
        int is = sel[wv][sR];
        float v = rnbf(bx[is*3 + c]);
        out[OUT_GX + (size_t)q*(NSAMPLE*3) + e] = v;
        out[(size_t)q*(NSAMPLE*ROWF) + sR*ROWF + c] = v;
    }

    // new_points feature columns: 32 rows x 64 feats, 256 B contiguous per row
    const float* prow = points + (size_t)b * NDATA * CFEAT;
    float* onp = out + (size_t)q * (NSAMPLE*ROWF);
    #pragma unroll 4
    for (int r = 0; r < NSAMPLE; ++r) {
        int is = sel[wv][r];
        onp[r*ROWF + 3 + lane] = rnbf(prow[(size_t)is * CFEAT + lane]);
    }
}

extern "C" void kernel_launch(void* const* d_in, const int* in_sizes, int n_in,
                              void* d_out, int out_size, void* d_ws, size_t ws_size,
                              hipStream_t stream) {
    // T = smallest f32 x with sqrtf(x) >= 0.2f  =>  (d2 < T) == (sqrtf(d2) < 0.2f)
    union { u32 u; float f; } lo, hi, mid;
    lo.u = 0u; hi.f = 0.05f;
    while (hi.u - lo.u > 1u) {
        mid.u = lo.u + (hi.u - lo.u) / 2u;
        if (sqrtf(mid.f) >= 0.2f) hi.u = mid.u; else lo.u = mid.u;
    }
    float T = hi.f;

    grouping_kernel<<<(BATCH*NPOINT)/4, 256, 0, stream>>>(
        (const float*)d_in[0],   // new_xyz (f32)
        (const float*)d_in[1],   // xyz     (f32)
        (const float*)d_in[2],   // points  (f32)
        (float*)d_out, T);
}

// Round 9
// 164.454 us; speedup vs baseline: 1.2540x; 1.2540x over previous
//
#include <hip/hip_runtime.h>
#include <math.h>

typedef unsigned int   u32;
typedef unsigned long long u64;

#define BATCH   8
#define NDATA   8192
#define NPOINT  1024
#define NSAMPLE 32
#define CFEAT   64
#define ROWF    67          // 3 xyz + 64 feat
#define MAXCAND 128         // P(#in-radius > 128) ~ 0 (lambda <= ~18)
#define QPW     2           // queries per wave
#define QPB     8           // queries per block (4 waves)

// f32-element offsets of the concatenated outputs
#define OUT_IDX (BATCH*NPOINT*NSAMPLE*ROWF)              // 17563648
#define OUT_GX  (OUT_IDX + BATCH*NPOINT*NSAMPLE)         // 17825792

// f32 -> bf16 (RNE) -> f32: match the harness's bf16-rounded np reference
__device__ __forceinline__ float rnbf(float f) {
    u32 b = __float_as_uint(f);
    b += 0x7FFFu + ((b >> 16) & 1u);
    return __uint_as_float(b & 0xFFFF0000u);
}
__device__ __forceinline__ int clampidx(int v) {
    return (v < 0) ? 0 : (v > NDATA-1 ? NDATA-1 : v);
}

__global__ __launch_bounds__(256)
void grouping_kernel(const float* __restrict__ new_xyz,
                     const float* __restrict__ xyz,
                     const float* __restrict__ points,
                     float* __restrict__ out, float T)
{
    __shared__ float cand_s[QPB][MAXCAND];   // f32 sqrt(d2), slot order = ascending idx
    __shared__ int   cand_i[QPB][MAXCAND];
    __shared__ int   sel[QPB][NSAMPLE];

    const int tid   = threadIdx.x;
    const int wv    = tid >> 6;
    const int lane  = tid & 63;
    const int qbase = blockIdx.x * QPB + wv * QPW;   // wave's first query, < 8192
    const int b     = qbase >> 10;                   // all QPB queries same batch

    // init this wave's sel rows (2 rows x 32 = 64 lanes)
    sel[wv*QPW + (lane >> 5)][lane & 31] = 0;

    float qx[QPW], qy[QPW], qz[QPW];
    #pragma unroll
    for (int j = 0; j < QPW; ++j) {
        qx[j] = new_xyz[(qbase+j)*3 + 0];
        qy[j] = new_xyz[(qbase+j)*3 + 1];
        qz[j] = new_xyz[(qbase+j)*3 + 2];
    }
    const float* bx = xyz + (size_t)b * NDATA * 3;   // 96 KB/batch, L2-resident

    // ---- scan: 2 queries per loaded point (latency hidden by VALU) ----
    float mind[QPW]; int mini[QPW]; int n[QPW];
    #pragma unroll
    for (int j = 0; j < QPW; ++j) { mind[j] = 3.402823466e38f; mini[j] = 0; n[j] = 0; }
    const u64 ltmask = (1ull << lane) - 1ull;

    for (int k = 0; k < NDATA/64; ++k) {
        int i = (k << 6) + lane;
        float x = bx[i*3 + 0];
        float y = bx[i*3 + 1];
        float z = bx[i*3 + 2];
        #pragma unroll
        for (int j = 0; j < QPW; ++j) {
            // exact np f32 semantics: no FMA, left-to-right sum
            float dx = __fsub_rn(x, qx[j]), dy = __fsub_rn(y, qy[j]), dz = __fsub_rn(z, qz[j]);
            float d2 = __fadd_rn(__fadd_rn(__fmul_rn(dx,dx), __fmul_rn(dy,dy)),
                                 __fmul_rn(dz,dz));
            if (d2 < mind[j]) { mind[j] = d2; mini[j] = i; }  // strict <: lowest idx/lane
            bool c = d2 < T;                    // == sqrtf(d2) < 0.2f (monotone)
            u64 m = __ballot(c);
            if (c) {
                int pos = n[j] + (int)__popcll(m & ltmask);
                if (pos < MAXCAND) {
                    cand_s[wv*QPW + j][pos] = __fsqrt_rn(d2);  // ref sorts the f32 norm
                    cand_i[wv*QPW + j][pos] = i;
                }
            }
            n[j] += (int)__popcll(m);
        }
    }

    // wave-reduce argmin per query (np tie rule on sqrt values, lowest index)
    float minS[QPW];
    #pragma unroll
    for (int j = 0; j < QPW; ++j) {
        minS[j] = __fsqrt_rn(mind[j]);
        for (int off = 32; off; off >>= 1) {
            float os = __shfl_xor(minS[j], off);
            int   oi = __shfl_xor(mini[j], off);
            if (os < minS[j] || (os == minS[j] && oi < mini[j])) { minS[j] = os; mini[j] = oi; }
        }
    }

    __syncthreads();   // uniform (fixed 128 iters); publish compaction + sel init

    // ---- parallel rank-place: (s, slot) lex == stable argsort by distance ----
    #pragma unroll
    for (int j = 0; j < QPW; ++j) {
        int wq = wv*QPW + j;
        int nj = n[j] > MAXCAND ? MAXCAND : n[j];
        for (int kk = lane; kk < nj; kk += 64) {
            float sk = cand_s[wq][kk];
            int r = 0;
            for (int mm = 0; mm < nj; ++mm) {     // broadcast LDS reads, conflict-free
                float sm = cand_s[wq][mm];
                r += (int)((sm < sk) | ((sm == sk) & (mm < kk)));
            }
            if (r < NSAMPLE) sel[wq][r] = clampidx(cand_i[wq][kk]);
        }
    }
    __syncthreads();
    #pragma unroll
    for (int j = 0; j < QPW; ++j) {
        int wq = wv*QPW + j;
        int nj = n[j] > MAXCAND ? MAXCAND : n[j];
        int nsel = nj < NSAMPLE ? nj : NSAMPLE;
        if (lane >= nsel && lane < NSAMPLE) {
            int pad = (nj > 0) ? sel[wq][0] : clampidx(mini[j]);   // sorted_idx[0]
            sel[wq][lane] = pad;
        }
    }
    __syncthreads();

    // ---- outputs: f32 stores, values pre-rounded through bf16 ----
    #pragma unroll
    for (int j = 0; j < QPW; ++j) {
        const int q  = qbase + j;
        const int wq = wv*QPW + j;

        // idx (chunk 1)
        if (lane < NSAMPLE)
            out[OUT_IDX + (size_t)q*NSAMPLE + lane] = rnbf((float)sel[wq][lane]);

        // grouped_xyz (chunk 2) + xyz columns of new_points (chunk 0)
        for (int e = lane; e < NSAMPLE*3; e += 64) {
            int sR = e / 3, c = e - sR*3;
            int is = sel[wq][sR];
            float v = rnbf(bx[is*3 + c]);
            out[OUT_GX + (size_t)q*(NSAMPLE*3) + e] = v;
            out[(size_t)q*(NSAMPLE*ROWF) + sR*ROWF + c] = v;
        }

        // new_points feature columns: 32 rows x 64 feats, 256 B contiguous/row
        const float* prow = points + (size_t)b * NDATA * CFEAT;
        float* onp = out + (size_t)q * (NSAMPLE*ROWF);
        #pragma unroll 4
        for (int r = 0; r < NSAMPLE; ++r) {
            int is = sel[wq][r];
            onp[r*ROWF + 3 + lane] = rnbf(prow[(size_t)is * CFEAT + lane]);
        }
    }
}

extern "C" void kernel_launch(void* const* d_in, const int* in_sizes, int n_in,
                              void* d_out, int out_size, void* d_ws, size_t ws_size,
                              hipStream_t stream) {
    // T = smallest f32 x with sqrtf(x) >= 0.2f  =>  (d2 < T) == (sqrtf(d2) < 0.2f)
    union { u32 u; float f; } lo, hi, mid;
    lo.u = 0u; hi.f = 0.05f;
    while (hi.u - lo.u > 1u) {
        mid.u = lo.u + (hi.u - lo.u) / 2u;
        if (sqrtf(mid.f) >= 0.2f) hi.u = mid.u; else lo.u = mid.u;
    }
    float T = hi.f;

    grouping_kernel<<<(BATCH*NPOINT)/QPB, 256, 0, stream>>>(
        (const float*)d_in[0],   // new_xyz (f32)
        (const float*)d_in[1],   // xyz     (f32)
        (const float*)d_in[2],   // points  (f32)
        (float*)d_out, T);
}